// Round 1
// baseline (165.668 us; speedup 1.0000x reference)
//
#include <hip/hip_runtime.h>

// EfficientAttention: x(4,256,64,64) -> qkv(192ch) -> attn(N=4096,c=64) -> proj(256ch)
// K1: qkv GEMM (MFMA 32x32x16 bf16), writes Q,K as (B,N,64) bf16; V as (B,64,N) bf16 into d_ws.
// K2: flash attention (S^T = K^T Q, unnormalized softmax, O^T = V P^T) + fused proj + bias.

#define N_TOK 4096
#define CDIM  64
#define DIM   256
#define NBAT  4

typedef __attribute__((ext_vector_type(8)))  short          short8;
typedef __attribute__((ext_vector_type(8)))  unsigned short ushort8_t;
typedef __attribute__((ext_vector_type(4)))  unsigned short ushort4_t;
typedef __attribute__((ext_vector_type(4)))  float          float4_t;
typedef __attribute__((ext_vector_type(16))) float          float16_t;

__device__ __forceinline__ unsigned short f2bf(float f) {
  unsigned int u = __builtin_bit_cast(unsigned int, f);
  u += 0x7fffu + ((u >> 16) & 1u);            // RNE
  return (unsigned short)(u >> 16);
}

__device__ __forceinline__ short8 ld8(const unsigned short* p) {
  return __builtin_bit_cast(short8, *(const ushort8_t*)p);
}

__device__ __forceinline__ short8 pack8(float4_t a, float4_t b) {
  ushort8_t r;
  r[0] = f2bf(a[0]); r[1] = f2bf(a[1]); r[2] = f2bf(a[2]); r[3] = f2bf(a[3]);
  r[4] = f2bf(b[0]); r[5] = f2bf(b[1]); r[6] = f2bf(b[2]); r[7] = f2bf(b[3]);
  return __builtin_bit_cast(short8, r);
}

__device__ __forceinline__ float16_t z16() {
  float16_t r;
#pragma unroll
  for (int i = 0; i < 16; ++i) r[i] = 0.0f;
  return r;
}

#define MFMA(a, b, c) __builtin_amdgcn_mfma_f32_32x32x16_bf16((a), (b), (c), 0, 0, 0)

// ---------------------------------------------------------------------------
// Kernel 1: qkv[o][n] = sum_c W[o][c] x[c][n] + bias[o]   (per batch)
// grid (64, 4), 256 threads. Block: n-tile of 64, all 192 o.
// A = W (o x c) from global fp32 (cvt to bf16 in regs); B = x staged+transposed
// in LDS as Xl[n][c] bf16. C rows=o, cols=n (col = lane&31).
// ---------------------------------------------------------------------------
#define XS 264   // Xl row stride (elements); 264*2=528 bytes, 16B-aligned rows

__global__ __launch_bounds__(256, 1) void k_qkv(
    const float* __restrict__ x, const float* __restrict__ w,
    const float* __restrict__ bias, unsigned short* __restrict__ qo,
    unsigned short* __restrict__ ko, unsigned short* __restrict__ vo)
{
  __shared__ __align__(16) unsigned short Xl[64 * XS];
  const int t  = threadIdx.x;
  const int b  = blockIdx.y, nt = blockIdx.x;

  // stage x tile (256 c x 64 n) transposed -> Xl[n][c] bf16
  const int n4 = (t & 15) * 4;
  const int c0 = t >> 4;
#pragma unroll
  for (int p = 0; p < 16; ++p) {
    int c = c0 + p * 16;
    float4_t f = *(const float4_t*)(x + ((b * DIM + c) << 12) + nt * 64 + n4);
    Xl[(n4 + 0) * XS + c] = f2bf(f[0]);
    Xl[(n4 + 1) * XS + c] = f2bf(f[1]);
    Xl[(n4 + 2) * XS + c] = f2bf(f[2]);
    Xl[(n4 + 3) * XS + c] = f2bf(f[3]);
  }
  __syncthreads();

  const int lane = t & 63, wv = t >> 6;
  const int l31 = lane & 31, lh = lane >> 5;
  const int ntile = wv & 1;            // 0/1 (n sub-tile of 32)
  const int ob    = (wv >> 1) * 3;     // o-tiles 0..2 or 3..5

  float16_t acc[3] = { z16(), z16(), z16() };

  const unsigned short* xrow = &Xl[(ntile * 32 + l31) * XS + lh * 8];
  const float* wrow = w + (ob * 32 + l31) * 256 + lh * 8;

#pragma unroll 4
  for (int kk = 0; kk < 16; ++kk) {
    short8 bf = ld8(xrow + kk * 16);
#pragma unroll
    for (int ot = 0; ot < 3; ++ot) {
      float4_t wa = *(const float4_t*)(wrow + ot * 32 * 256 + kk * 16);
      float4_t wb = *(const float4_t*)(wrow + ot * 32 * 256 + kk * 16 + 4);
      acc[ot] = MFMA(pack8(wa, wb), bf, acc[ot]);
    }
  }

  // epilogue: +bias, cast bf16, scatter to Q (B,N,64) / K (B,N,64) / V (B,64,N)
  const int nglob = nt * 64 + ntile * 32 + l31;
#pragma unroll
  for (int ot = 0; ot < 3; ++ot) {
    int otile = ob + ot;  // 0..5 : 0,1->Q  2,3->K  4,5->V
#pragma unroll
    for (int p = 0; p < 4; ++p) {
      int obase = otile * 32 + p * 8 + lh * 4;   // +0..3 = o of the reg quad
      ushort4_t pk;
#pragma unroll
      for (int qq = 0; qq < 4; ++qq)
        pk[qq] = f2bf(acc[ot][p * 4 + qq] + bias[obase + qq]);
      if (otile < 2) {
        *(ushort4_t*)(qo + ((b * N_TOK + nglob) << 6) + obase) = pk;
      } else if (otile < 4) {
        *(ushort4_t*)(ko + ((b * N_TOK + nglob) << 6) + (obase - 64)) = pk;
      } else {
        int cc = obase - 128;
        unsigned short* vp = vo + ((b * CDIM + cc) << 12) + nglob;
        vp[0] = pk[0]; vp[4096] = pk[1]; vp[8192] = pk[2]; vp[12288] = pk[3];
      }
    }
  }
}

// ---------------------------------------------------------------------------
// Kernel 2: flash attention + fused proj.
// grid (64, 4), 256 threads (4 waves). Block: 64 q-rows.
// wave w: q-rows (w>>1)*32 .. +31, m-chunks of 32 with parity (w&1).
// S^T = K^T Q  (A=K from global, B=Q regs)  -> P=exp(S*0.125), den[n] scalar/lane
// O^T = V P^T  (A=V from global, B=P^T via per-wave LDS, double-buffered)
// combine wave pairs + normalize -> Ol[n][cc] bf16 -> proj MFMA + bias -> out.
// ---------------------------------------------------------------------------
#define PS   40    // Pl row stride (elements): 80B rows, 16B-aligned
#define PLSZ (32 * PS)
#define OS   68    // Ofp row stride (fp32)
#define OLS  72    // Ol row stride (bf16)

__global__ __launch_bounds__(256, 1) void k_attn(
    const unsigned short* __restrict__ Qb, const unsigned short* __restrict__ Kb,
    const unsigned short* __restrict__ Vb, const float* __restrict__ pw,
    const float* __restrict__ pb, float* __restrict__ out)
{
  __shared__ __align__(16) unsigned short Pl[4][2 * PLSZ];  // per-wave, dbuf
  __shared__ __align__(16) float Ofp[4][32 * OS];           // per-wave O^T (unnorm)
  __shared__ float denw[4][32];
  __shared__ __align__(16) unsigned short Ol[64 * OLS];     // combined O, [n][cc] bf16

  const int t = threadIdx.x;
  const int b = blockIdx.y, nt = blockIdx.x;
  const int lane = t & 63, wv = t >> 6;
  const int l31 = lane & 31, lh = lane >> 5;
  const int rowh = wv >> 1;                 // q-row half
  const int nglob = nt * 64 + rowh * 32 + l31;

  // Q B-frags (c x n), col n = l31 -> row nglob, 8 contiguous c per kstep
  short8 qf[4];
#pragma unroll
  for (int kk = 0; kk < 4; ++kk)
    qf[kk] = ld8(Qb + ((b * N_TOK + nglob) << 6) + kk * 16 + lh * 8);

  const unsigned short* kb = Kb + ((b * N_TOK) << 6) + (l31 << 6) + lh * 8;
  const unsigned short* vb = Vb + ((b * CDIM + l31) << 12) + lh * 8;

  float16_t oacc0 = z16(), oacc1 = z16();
  float den = 0.0f;
  const int mst = wv & 1;

  short8 kf[4], vf[4];
#pragma unroll
  for (int kk = 0; kk < 4; ++kk) kf[kk] = ld8(kb + (mst * 32) * 64 + kk * 16);
#pragma unroll
  for (int i = 0; i < 4; ++i) {
    int ct = i >> 1, k2 = i & 1;
    vf[i] = ld8(vb + ct * (32 * 4096) + mst * 32 + k2 * 16);
  }

  unsigned short* plbase = &Pl[wv][l31 * PS];

  for (int it = 0; it < 64; ++it) {
    const int mc = 2 * it + mst;
    short8 kn[4], vn[4];
    const bool more = (it < 63);
    if (more) {
      const int mn = mc + 2;
#pragma unroll
      for (int kk = 0; kk < 4; ++kk) kn[kk] = ld8(kb + (mn * 32) * 64 + kk * 16);
#pragma unroll
      for (int i = 0; i < 4; ++i) {
        int ct = i >> 1, k2 = i & 1;
        vn[i] = ld8(vb + ct * (32 * 4096) + mn * 32 + k2 * 16);
      }
    }

    // S^T tile (32m x 32n): rows m = (e&3)+8(e>>2)+4lh, col n = l31
    float16_t s = z16();
#pragma unroll
    for (int kk = 0; kk < 4; ++kk) s = MFMA(kf[kk], qf[kk], s);

    float p[16];
#pragma unroll
    for (int e = 0; e < 16; ++e) p[e] = __expf(s[e] * 0.125f);
    {
      float d0 = (p[0] + p[1]) + (p[2] + p[3]);
      float d1 = (p[4] + p[5]) + (p[6] + p[7]);
      float d2 = (p[8] + p[9]) + (p[10] + p[11]);
      float d3 = (p[12] + p[13]) + (p[14] + p[15]);
      den += (d0 + d1) + (d2 + d3);
    }

    unsigned short* plrow = plbase + (it & 1) * PLSZ;
#pragma unroll
    for (int pp = 0; pp < 4; ++pp) {
      ushort4_t pk;
#pragma unroll
      for (int qq = 0; qq < 4; ++qq) pk[qq] = f2bf(p[pp * 4 + qq]);
      *(ushort4_t*)(plrow + pp * 8 + lh * 4) = pk;   // m = qq + 8pp + 4lh
    }

    // P^T B-frags: col n = l31, k = m (8 contiguous)
    short8 pf0 = ld8(plrow + lh * 8);
    short8 pf1 = ld8(plrow + 16 + lh * 8);
    oacc0 = MFMA(vf[0], pf0, oacc0);
    oacc0 = MFMA(vf[1], pf1, oacc0);
    oacc1 = MFMA(vf[2], pf0, oacc1);
    oacc1 = MFMA(vf[3], pf1, oacc1);

    if (more) {
#pragma unroll
      for (int i = 0; i < 4; ++i) { kf[i] = kn[i]; vf[i] = vn[i]; }
    }
  }

  // full den[n] for this wave's m-parity + the complementary lane half
  den += __shfl_xor(den, 32);

  // write unnormalized O^T to LDS: Ofp[wv][n=l31][cc], cc quads contiguous
#pragma unroll
  for (int ct = 0; ct < 2; ++ct) {
    const float16_t& oa = ct ? oacc1 : oacc0;
#pragma unroll
    for (int pp = 0; pp < 4; ++pp) {
      float4_t o4;
#pragma unroll
      for (int qq = 0; qq < 4; ++qq) o4[qq] = oa[pp * 4 + qq];
      *(float4_t*)&Ofp[wv][l31 * OS + ct * 32 + pp * 8 + lh * 4] = o4;
    }
  }
  if (lane < 32) denw[wv][l31] = den;
  __syncthreads();

  // combine wave pairs, normalize, cast -> Ol[n][cc] bf16
  {
    const int n = t >> 2, cq = (t & 3) << 4;
    const int nl = n & 31, w0 = (n >> 5) << 1;
    const float r = 1.0f / (denw[w0][nl] + denw[w0 + 1][nl]);
    ushort8_t o8[2];
#pragma unroll
    for (int i = 0; i < 4; ++i) {
      float4_t a = *(float4_t*)&Ofp[w0][nl * OS + cq + i * 4];
      float4_t c = *(float4_t*)&Ofp[w0 + 1][nl * OS + cq + i * 4];
#pragma unroll
      for (int qq = 0; qq < 4; ++qq)
        o8[i >> 1][(i & 1) * 4 + qq] = f2bf((a[qq] + c[qq]) * r);
    }
    *(ushort8_t*)&Ol[n * OLS + cq] = o8[0];
    *(ushort8_t*)&Ol[n * OLS + cq + 8] = o8[1];
  }
  __syncthreads();

  // fused proj: F[o][n] = sum_cc W[o][cc] * O[n][cc] + pb[o]
  float16_t f00 = z16(), f01 = z16(), f10 = z16(), f11 = z16();
  const float* pwrow = pw + (wv * 64 + l31) * 64 + lh * 8;
#pragma unroll
  for (int kk = 0; kk < 4; ++kk) {
    short8 bf0 = ld8(&Ol[l31 * OLS + kk * 16 + lh * 8]);
    short8 bf1 = ld8(&Ol[(32 + l31) * OLS + kk * 16 + lh * 8]);
    {
      float4_t wa = *(const float4_t*)(pwrow + kk * 16);
      float4_t wb = *(const float4_t*)(pwrow + kk * 16 + 4);
      short8 af = pack8(wa, wb);
      f00 = MFMA(af, bf0, f00);
      f01 = MFMA(af, bf1, f01);
    }
    {
      float4_t wa = *(const float4_t*)(pwrow + 32 * 64 + kk * 16);
      float4_t wb = *(const float4_t*)(pwrow + 32 * 64 + kk * 16 + 4);
      short8 af = pack8(wa, wb);
      f10 = MFMA(af, bf0, f10);
      f11 = MFMA(af, bf1, f11);
    }
  }
  const int n0 = nt * 64;
#pragma unroll
  for (int ot = 0; ot < 2; ++ot) {
    const float16_t& fa = ot ? f10 : f00;
    const float16_t& fb = ot ? f11 : f01;
#pragma unroll
    for (int e = 0; e < 16; ++e) {
      int o = wv * 64 + ot * 32 + (e & 3) + ((e >> 2) * 8) + lh * 4;
      float bv = pb[o];
      out[((b * 256 + o) << 12) + n0 + l31]      = fa[e] + bv;
      out[((b * 256 + o) << 12) + n0 + 32 + l31] = fb[e] + bv;
    }
  }
}

extern "C" void kernel_launch(void* const* d_in, const int* in_sizes, int n_in,
                              void* d_out, int out_size, void* d_ws, size_t ws_size,
                              hipStream_t stream) {
  const float* x      = (const float*)d_in[0];
  const float* qkv_w  = (const float*)d_in[1];
  const float* qkv_b  = (const float*)d_in[2];
  const float* proj_w = (const float*)d_in[3];
  const float* proj_b = (const float*)d_in[4];
  float* out = (float*)d_out;

  // workspace: Q (B,N,64) | K (B,N,64) | V (B,64,N), bf16 -> 6 MB total
  unsigned short* q = (unsigned short*)d_ws;
  unsigned short* k = q + (size_t)NBAT * N_TOK * CDIM;
  unsigned short* v = k + (size_t)NBAT * N_TOK * CDIM;

  dim3 grid(64, 4);
  k_qkv<<<grid, 256, 0, stream>>>(x, qkv_w, qkv_b, q, k, v);
  k_attn<<<grid, 256, 0, stream>>>(q, k, v, proj_w, proj_b, out);
}

// Round 3
// 163.488 us; speedup vs baseline: 1.0133x; 1.0133x over previous
//
#include <hip/hip_runtime.h>

// EfficientAttention: x(4,256,64,64) -> qkv(192ch) -> attn(N=4096,c=64) -> proj(256ch)
// k_prep: weights fp32->bf16 once (softmax scale folded into Q rows/bias).
// k_qkv : MFMA 32x32x16 bf16; Q,K as (B,N,64), V as (B,64,N) bf16 in ws.
// k_attn: flash attn, S^T = K^T Q, P transposed to B-frag via shfl_xor (no LDS
//         round-trip), O^T = V P^T, parity-wave combine via LDS ds_add_f32,
//         fused 64->256 proj + bias.

#define N_TOK 4096
#define CDIM  64
#define DIM   256
#define NBAT  4

typedef __attribute__((ext_vector_type(8)))  short          short8;
typedef __attribute__((ext_vector_type(8)))  unsigned short ushort8_t;
typedef __attribute__((ext_vector_type(4)))  unsigned short ushort4_t;
typedef __attribute__((ext_vector_type(4)))  unsigned int   uint4_t;
typedef __attribute__((ext_vector_type(4)))  float          float4_t;
typedef __attribute__((ext_vector_type(16))) float          float16_t;

#if __has_builtin(__builtin_amdgcn_exp2f)
#define QSC  0.18033688011112042f   /* 0.125 * log2(e): p = exp2(s) */
#define PEXP(x) __builtin_amdgcn_exp2f(x)
#else
#define QSC  0.125f
#define PEXP(x) __expf(x)
#endif

__device__ __forceinline__ unsigned short f2bf(float f) {
  unsigned int u = __builtin_bit_cast(unsigned int, f);
  u += 0x7fffu + ((u >> 16) & 1u);            // RNE
  return (unsigned short)(u >> 16);
}

// pack (a,b) -> bf16x2 dword, a in low half (RNE both halves)
__device__ __forceinline__ unsigned int pkbf(float a, float b) {
  return (unsigned int)f2bf(a) | ((unsigned int)f2bf(b) << 16);
}

__device__ __forceinline__ short8 ld8(const unsigned short* p) {
  return __builtin_bit_cast(short8, *(const ushort8_t*)p);
}

__device__ __forceinline__ float16_t z16() {
  float16_t r;
#pragma unroll
  for (int i = 0; i < 16; ++i) r[i] = 0.0f;
  return r;
}

#define MFMA(a, b, c) __builtin_amdgcn_mfma_f32_32x32x16_bf16((a), (b), (c), 0, 0, 0)

// ws layout (u16 units)
#define QOFF  0
#define KOFF  1048576          // 4*4096*64
#define VOFF  2097152
#define WQOFF 3145728          // qkv_w bf16: 192*256
#define WPOFF 3194880          // proj_w bf16: 256*64
#define BSOFF 3211264          // scaled qkv bias, fp32 (192)

// ---------------------------------------------------------------------------
// k_prep: grid 64 x 256. qkv_w (12288 float4) + proj_w (4096 float4) -> bf16;
// bias -> fp32 with Q-scale fold.
// ---------------------------------------------------------------------------
__global__ void k_prep(const float* __restrict__ qw, const float* __restrict__ qb,
                       const float* __restrict__ pw, unsigned short* __restrict__ wq,
                       unsigned short* __restrict__ wp, float* __restrict__ bs)
{
  int g = blockIdx.x * 256 + threadIdx.x;
  if (g < 12288) {
    float4_t f = *(const float4_t*)(qw + g * 4);
    float sc = ((g >> 6) < 64) ? QSC : 1.0f;   // row o = g/64 (256 floats/row)
    ushort4_t u;
#pragma unroll
    for (int j = 0; j < 4; ++j) u[j] = f2bf(f[j] * sc);
    *(ushort4_t*)(wq + g * 4) = u;
  } else {
    int i = g - 12288;                          // < 4096
    float4_t f = *(const float4_t*)(pw + i * 4);
    ushort4_t u;
#pragma unroll
    for (int j = 0; j < 4; ++j) u[j] = f2bf(f[j]);
    *(ushort4_t*)(wp + i * 4) = u;
  }
  if (g < 48) {
    float4_t f = *(const float4_t*)(qb + g * 4);
    float4_t o;
#pragma unroll
    for (int j = 0; j < 4; ++j) o[j] = f[j] * ((g * 4 + j) < 64 ? QSC : 1.0f);
    *(float4_t*)(bs + g * 4) = o;
  }
}

// ---------------------------------------------------------------------------
// k_qkv: grid 512 x 384 thr (6 waves). Block: n-tile of 32, all 192 o.
// Xl[n][cpair] dwords (bf16x2, c ascending) -> B-frags are ds_read_b128.
// ---------------------------------------------------------------------------
#define RS 132   // Xl row stride in dwords (128 data + 4 pad), 16B-aligned

__global__ __launch_bounds__(384, 3) void k_qkv(
    const float* __restrict__ x, const unsigned short* __restrict__ wq,
    const float* __restrict__ bs, unsigned short* __restrict__ qo,
    unsigned short* __restrict__ ko, unsigned short* __restrict__ vo)
{
  __shared__ unsigned int Xl[32 * RS];
  const int id = blockIdx.x;
  const int b  = (id >> 1) & 3;
  const int nt = (id & 1) | ((id >> 3) << 1);   // 0..127
  const int t  = threadIdx.x;
  const int n0g = nt * 32;

  if (t < 256) {
    const int n0  = (t & 7) * 4;
    const int cpb = t >> 3;                      // 0..31
#pragma unroll
    for (int p = 0; p < 4; ++p) {
      const int cp = cpb + 32 * p, c = cp * 2;
      const float* xb = x + (((size_t)(b * DIM + c)) << 12) + n0g + n0;
      float4_t a = *(const float4_t*)xb;
      float4_t d = *(const float4_t*)(xb + 4096);
#pragma unroll
      for (int j = 0; j < 4; ++j)
        Xl[(n0 + j) * RS + cp] = pkbf(a[j], d[j]);
    }
  }
  __syncthreads();

  const int w = t >> 6, lane = t & 63, l31 = lane & 31, lh = lane >> 5;
  float16_t acc = z16();
  const unsigned short* wrow = wq + (w * 32 + l31) * 256 + lh * 8;
  const unsigned int*   xrow = &Xl[l31 * RS + lh * 4];

#pragma unroll
  for (int kk = 0; kk < 16; ++kk) {
    short8 bfr = __builtin_bit_cast(short8, *(const uint4_t*)(xrow + kk * 8));
    short8 afr = ld8(wrow + kk * 16);
    acc = MFMA(afr, bfr, acc);
  }

  const int nglob = n0g + l31;
#pragma unroll
  for (int p = 0; p < 4; ++p) {
    const int ol = p * 8 + lh * 4;
    const int o  = w * 32 + ol;
    float4_t bv = *(const float4_t*)(bs + o);
    ushort4_t pk4;
#pragma unroll
    for (int q = 0; q < 4; ++q) pk4[q] = f2bf(acc[p * 4 + q] + bv[q]);
    if (w < 2) {
      *(ushort4_t*)(qo + ((b * N_TOK + nglob) << 6) + o) = pk4;
    } else if (w < 4) {
      *(ushort4_t*)(ko + ((b * N_TOK + nglob) << 6) + (o - 64)) = pk4;
    } else {
      const int cc = o - 128;
      unsigned short* vp = vo + ((b * CDIM + cc) << 12) + nglob;
      vp[0] = pk4[0]; vp[4096] = pk4[1]; vp[8192] = pk4[2]; vp[12288] = pk4[3];
    }
  }
}

// ---------------------------------------------------------------------------
// k_attn: grid 256 x 512 thr (8 waves). Block: 64 q-rows.
// wave wv: n-subtile (wv&1), m-parity (wv>>1), 32 iters of 32-m chunks.
// P transpose to B-frag: 4x shfl_xor(32) of packed bf16x2 dwords.
// Parity combine: LDS ds_add_f32 into Oacc, then normalize -> Ol bf16 -> proj.
// ---------------------------------------------------------------------------
#define OS   68    // Oacc row stride (fp32)
#define OLS  72    // Ol row stride (bf16); 144B rows, 16B-aligned
#define NACC (64 * OS + 64)

__global__ __launch_bounds__(512, 2) void k_attn(
    const unsigned short* __restrict__ Qb, const unsigned short* __restrict__ Kb,
    const unsigned short* __restrict__ Vb, const unsigned short* __restrict__ wp,
    const float* __restrict__ pb, float* __restrict__ out)
{
  __shared__ float Oacc[NACC];                       // O^T partial + den at tail
  __shared__ __align__(16) unsigned short Ol[64 * OLS];

  const int id = blockIdx.x;
  const int b  = (id >> 1) & 3;
  const int nt = (id & 1) | ((id >> 3) << 1);        // 0..63
  const int t  = threadIdx.x;
  const int wv = t >> 6, lane = t & 63, l31 = lane & 31, lh = lane >> 5;
  const int nsub = wv & 1, par = wv >> 1;
  const int nglob = nt * 64 + nsub * 32 + l31;

  for (int i = t; i < NACC; i += 512) Oacc[i] = 0.0f;

  // Q B-frags (pre-scaled by QSC via k_prep weight fold)
  short8 qf[4];
#pragma unroll
  for (int kk = 0; kk < 4; ++kk)
    qf[kk] = ld8(Qb + ((b * N_TOK + nglob) << 6) + kk * 16 + lh * 8);

  const unsigned short* kb = Kb + ((b * N_TOK) << 6) + (l31 << 6) + lh * 8;
  const unsigned short* vb = Vb + ((b * CDIM + l31) << 12) + lh * 8;

  __syncthreads();   // Oacc zeroed

  float16_t oacc0 = z16(), oacc1 = z16();
  float den = 0.0f;

  short8 kf[2][4], vf[2][4];
  int mc = par;                                      // chunk = 4*it + par
#pragma unroll
  for (int kk = 0; kk < 4; ++kk) kf[0][kk] = ld8(kb + mc * 2048 + kk * 16);
#pragma unroll
  for (int i = 0; i < 4; ++i) {
    int ct = i >> 1, ks = i & 1;
    vf[0][i] = ld8(vb + ct * (32 << 12) + mc * 32 + ks * 16);
  }

#pragma unroll 2
  for (int it = 0; it < 32; ++it) {
    const int cur = it & 1, nxt = cur ^ 1;
    const bool more = (it < 31);
    if (more) {
      const int mn = mc + 4;
#pragma unroll
      for (int kk = 0; kk < 4; ++kk) kf[nxt][kk] = ld8(kb + mn * 2048 + kk * 16);
#pragma unroll
      for (int i = 0; i < 4; ++i) {
        int ct = i >> 1, ks = i & 1;
        vf[nxt][i] = ld8(vb + ct * (32 << 12) + mn * 32 + ks * 16);
      }
    }

    // S^T tile: lane col n = l31, row m = (e&3)+8*(e>>2)+4*lh
    float16_t s = z16();
#pragma unroll
    for (int kk = 0; kk < 4; ++kk) s = MFMA(kf[cur][kk], qf[kk], s);

    float p[16];
#pragma unroll
    for (int e = 0; e < 16; ++e) p[e] = PEXP(s[e]);
    {
      float d0 = (p[0] + p[1]) + (p[2] + p[3]);
      float d1 = (p[4] + p[5]) + (p[6] + p[7]);
      float d2 = (p[8] + p[9]) + (p[10] + p[11]);
      float d3 = (p[12] + p[13]) + (p[14] + p[15]);
      den += (d0 + d1) + (d2 + d3);
    }

    // pack consecutive-m pairs into bf16x2 dwords
    unsigned int u[8];
#pragma unroll
    for (int j = 0; j < 8; ++j) u[j] = pkbf(p[2 * j], p[2 * j + 1]);

    // cross-half exchange -> P^T B-frags (k = m)
    unsigned int t0 = lh ? u[0] : u[2];
    unsigned int t1 = lh ? u[1] : u[3];
    unsigned int t2 = lh ? u[4] : u[6];
    unsigned int t3 = lh ? u[5] : u[7];
    unsigned int r0 = __shfl_xor(t0, 32);
    unsigned int r1 = __shfl_xor(t1, 32);
    unsigned int r2 = __shfl_xor(t2, 32);
    unsigned int r3 = __shfl_xor(t3, 32);
    uint4_t w0, w1;
    w0[0] = lh ? r0 : u[0]; w0[1] = lh ? r1 : u[1];
    w0[2] = lh ? u[2] : r0; w0[3] = lh ? u[3] : r1;
    w1[0] = lh ? r2 : u[4]; w1[1] = lh ? r3 : u[5];
    w1[2] = lh ? u[6] : r2; w1[3] = lh ? u[7] : r3;
    short8 pf0 = __builtin_bit_cast(short8, w0);
    short8 pf1 = __builtin_bit_cast(short8, w1);

    oacc0 = MFMA(vf[cur][0], pf0, oacc0);
    oacc0 = MFMA(vf[cur][1], pf1, oacc0);
    oacc1 = MFMA(vf[cur][2], pf0, oacc1);
    oacc1 = MFMA(vf[cur][3], pf1, oacc1);

    mc += 4;
  }

  den += __shfl_xor(den, 32);   // full chunk sum for this parity

  // accumulate partial O^T (rows c, cols n) + den into LDS
  {
    const int nrow = nsub * 32 + l31;
#pragma unroll
    for (int ct = 0; ct < 2; ++ct) {
      const float16_t& oa = ct ? oacc1 : oacc0;
#pragma unroll
      for (int pp = 0; pp < 4; ++pp) {
        const int cbase = ct * 32 + pp * 8 + lh * 4;
#pragma unroll
        for (int q = 0; q < 4; ++q)
          atomicAdd(&Oacc[nrow * OS + cbase + q], oa[pp * 4 + q]);
      }
    }
    if (lane < 32) atomicAdd(&Oacc[64 * OS + nrow], den);
  }
  __syncthreads();

  // normalize + cast -> Ol[n][c] bf16
  {
    const int nloc = t >> 3, c8 = (t & 7) * 8;
    float4_t s0 = *(float4_t*)&Oacc[nloc * OS + c8];
    float4_t s1 = *(float4_t*)&Oacc[nloc * OS + c8 + 4];
    const float r = 1.0f / Oacc[64 * OS + nloc];
    uint4_t o4;
    o4[0] = pkbf(s0[0] * r, s0[1] * r);
    o4[1] = pkbf(s0[2] * r, s0[3] * r);
    o4[2] = pkbf(s1[0] * r, s1[1] * r);
    o4[3] = pkbf(s1[2] * r, s1[3] * r);
    *(uint4_t*)&Ol[nloc * OLS + c8] = o4;
  }
  __syncthreads();

  // fused proj: wave wv -> o-tile wv (32 o), both n-subtiles
  float16_t f0 = z16(), f1 = z16();
  const unsigned short* wrow = wp + (wv * 32 + l31) * 64 + lh * 8;
#pragma unroll
  for (int kk = 0; kk < 4; ++kk) {
    short8 af = ld8(wrow + kk * 16);
    short8 b0 = ld8(&Ol[l31 * OLS + kk * 16 + lh * 8]);
    short8 b1 = ld8(&Ol[(32 + l31) * OLS + kk * 16 + lh * 8]);
    f0 = MFMA(af, b0, f0);
    f1 = MFMA(af, b1, f1);
  }
  const int n0 = nt * 64;
#pragma unroll
  for (int e = 0; e < 16; ++e) {
    const int o = wv * 32 + (e & 3) + 8 * (e >> 2) + 4 * lh;
    const float bv = pb[o];
    out[((b * 256 + o) << 12) + n0 + l31]      = f0[e] + bv;
    out[((b * 256 + o) << 12) + n0 + 32 + l31] = f1[e] + bv;
  }
}

extern "C" void kernel_launch(void* const* d_in, const int* in_sizes, int n_in,
                              void* d_out, int out_size, void* d_ws, size_t ws_size,
                              hipStream_t stream) {
  const float* x      = (const float*)d_in[0];
  const float* qkv_w  = (const float*)d_in[1];
  const float* qkv_b  = (const float*)d_in[2];
  const float* proj_w = (const float*)d_in[3];
  const float* proj_b = (const float*)d_in[4];
  float* out = (float*)d_out;

  unsigned short* ws = (unsigned short*)d_ws;
  unsigned short* q  = ws + QOFF;
  unsigned short* k  = ws + KOFF;
  unsigned short* v  = ws + VOFF;
  unsigned short* wq = ws + WQOFF;
  unsigned short* wp = ws + WPOFF;
  float*          bs = (float*)(ws + BSOFF);

  k_prep<<<64, 256, 0, stream>>>(qkv_w, qkv_b, proj_w, wq, wp, bs);
  k_qkv<<<512, 384, 0, stream>>>(x, wq, bs, q, k, v);
  k_attn<<<256, 512, 0, stream>>>(q, k, v, wp, proj_b, out);
}

// Round 4
// 146.604 us; speedup vs baseline: 1.1300x; 1.1152x over previous
//
#include <hip/hip_runtime.h>

// EfficientAttention: x(4,256,64,64) -> qkv(192ch) -> attn(N=4096,c=64) -> proj(256ch)
// All inter-kernel tensors live in MFMA-fragment-swizzled layouts so every
// global load/store in the hot loops is a fully-coalesced 16B/lane access.
//   Qf/Kf: [b][chunk32][kk(4)][lane(64)][8]   (frag outer = token, k = c)
//   Vf   : [b][chunk32][ct(2)][ks(2)][lane][8] (frag outer = c,     k = m)
//   wqs  : [w6(6)][kk(16)][lane][8]; wps: [wv(8)][kk(4)][lane][8]
// k_attn: S^T = K^T Q (A=Kf, B=Qf), P->A-frag via shfl_xor, O = P V (A=P, B=Vf),
//         8-way m-parity waves, LDS atomic combine, fused 64->256 proj + bias.

#define N_TOK 4096
#define CDIM  64
#define DIM   256
#define NBAT  4

typedef __attribute__((ext_vector_type(8)))  short          short8;
typedef __attribute__((ext_vector_type(8)))  unsigned short ushort8_t;
typedef __attribute__((ext_vector_type(4)))  unsigned short ushort4_t;
typedef __attribute__((ext_vector_type(4)))  unsigned int   uint4_t;
typedef __attribute__((ext_vector_type(4)))  float          float4_t;
typedef __attribute__((ext_vector_type(16))) float          float16_t;

#if __has_builtin(__builtin_amdgcn_exp2f)
#define QSC  0.18033688011112042f   /* 0.125 * log2(e): p = exp2(s) */
#define PEXP(x) __builtin_amdgcn_exp2f(x)
#else
#define QSC  0.125f
#define PEXP(x) __expf(x)
#endif

__device__ __forceinline__ unsigned short f2bf(float f) {
  unsigned int u = __builtin_bit_cast(unsigned int, f);
  u += 0x7fffu + ((u >> 16) & 1u);            // RNE
  return (unsigned short)(u >> 16);
}

__device__ __forceinline__ unsigned int pkbf(float a, float b) {
  return (unsigned int)f2bf(a) | ((unsigned int)f2bf(b) << 16);
}

__device__ __forceinline__ short8 ld8(const unsigned short* p) {
  return __builtin_bit_cast(short8, *(const ushort8_t*)p);
}

__device__ __forceinline__ float16_t z16() {
  float16_t r;
#pragma unroll
  for (int i = 0; i < 16; ++i) r[i] = 0.0f;
  return r;
}

#define MFMA(a, b, c) __builtin_amdgcn_mfma_f32_32x32x16_bf16((a), (b), (c), 0, 0, 0)

// ws layout (u16 units)
#define QOFF  0                // 4*128*4*512 = 1048576
#define KOFF  1048576
#define VOFF  2097152          // 4*128*2*2*512 = 1048576
#define WQOFF 3145728          // 192*256
#define WPOFF 3194880          // 256*64
#define BSOFF 3211264          // scaled qkv bias, fp32 (192)

// ---------------------------------------------------------------------------
// k_prep: grid 32 x 256. Swizzle qkv_w / proj_w into frag layouts (bf16),
// bias -> fp32 with Q-scale fold.
// ---------------------------------------------------------------------------
__global__ void k_prep(const float* __restrict__ qw, const float* __restrict__ qb,
                       const float* __restrict__ pw, unsigned short* __restrict__ wqs,
                       unsigned short* __restrict__ wps, float* __restrict__ bs)
{
  const int g = blockIdx.x * 256 + threadIdx.x;   // 0..8191
  if (g < 6144) {                                  // wqs: grp = w6*16+kk
    const int lane = g & 63, grp = g >> 6;
    const int w6 = grp >> 4, kk = grp & 15;
    const int o = w6 * 32 + (lane & 31);
    const int c = kk * 16 + (lane >> 5) * 8;
    const float sc = (o < 64) ? QSC : 1.0f;
    const float* src = qw + o * 256 + c;
    ushort8_t u;
#pragma unroll
    for (int j = 0; j < 8; ++j) u[j] = f2bf(src[j] * sc);
    *(ushort8_t*)(wqs + g * 8) = u;
  } else {                                         // wps: grp = wv*4+kk
    const int i = g - 6144;                        // < 2048
    const int lane = i & 63, grp = i >> 6;
    const int wv = grp >> 2, kk = grp & 3;
    const int o = wv * 32 + (lane & 31);
    const int c = kk * 16 + (lane >> 5) * 8;
    const float* src = pw + o * 64 + c;
    ushort8_t u;
#pragma unroll
    for (int j = 0; j < 8; ++j) u[j] = f2bf(src[j]);
    *(ushort8_t*)(wps + i * 8) = u;
  }
  if (g < 48) {
    float4_t f = *(const float4_t*)(qb + g * 4);
    float4_t o;
#pragma unroll
    for (int j = 0; j < 4; ++j) o[j] = f[j] * ((g * 4 + j) < 64 ? QSC : 1.0f);
    *(float4_t*)(bs + g * 4) = o;
  }
}

// ---------------------------------------------------------------------------
// k_qkv: grid 512 x 384 thr (6 waves). Block: n-tile of 32, all 192 o.
// Waves 0-3 (Q,K): C[o rows][n col=l31] -> frag stores (coalesced 512B).
// Waves 4-5 (V):   operands swapped -> C[n rows][c col=l31] -> Vf stores.
// ---------------------------------------------------------------------------
#define RS 132   // Xl row stride in dwords (128 data + 4 pad), 16B-aligned

__global__ __launch_bounds__(384, 3) void k_qkv(
    const float* __restrict__ x, const unsigned short* __restrict__ wqs,
    const float* __restrict__ bs, unsigned short* __restrict__ Qf,
    unsigned short* __restrict__ Kf, unsigned short* __restrict__ Vf)
{
  __shared__ unsigned int Xl[32 * RS];
  const int id = blockIdx.x;
  const int b  = (id >> 1) & 3;
  const int nt = (id & 1) | ((id >> 3) << 1);   // 0..127 (32-token chunk)
  const int t  = threadIdx.x;
  const int n0g = nt * 32;

  if (t < 256) {
    const int n0  = (t & 7) * 4;
    const int cpb = t >> 3;                      // 0..31
#pragma unroll
    for (int p = 0; p < 4; ++p) {
      const int cp = cpb + 32 * p, c = cp * 2;
      const float* xb = x + (((size_t)(b * DIM + c)) << 12) + n0g + n0;
      float4_t a = *(const float4_t*)xb;
      float4_t d = *(const float4_t*)(xb + 4096);
#pragma unroll
      for (int j = 0; j < 4; ++j)
        Xl[(n0 + j) * RS + cp] = pkbf(a[j], d[j]);
    }
  }
  __syncthreads();

  const int w = t >> 6, lane = t & 63, l31 = lane & 31, lh = lane >> 5;
  float16_t acc = z16();
  const unsigned short* wrow = wqs + ((w * 16) << 9) + lane * 8;
  const unsigned int*   xrow = &Xl[l31 * RS + lh * 4];

  if (w < 4) {
#pragma unroll
    for (int kk = 0; kk < 16; ++kk) {
      short8 bfr = __builtin_bit_cast(short8, *(const uint4_t*)(xrow + kk * 8));
      short8 afr = ld8(wrow + (kk << 9));
      acc = MFMA(afr, bfr, acc);                 // C[o rows][n cols]
    }
  } else {
#pragma unroll
    for (int kk = 0; kk < 16; ++kk) {
      short8 bfr = __builtin_bit_cast(short8, *(const uint4_t*)(xrow + kk * 8));
      short8 afr = ld8(wrow + (kk << 9));
      acc = MFMA(bfr, afr, acc);                 // C[n rows][c cols]
    }
  }

  if (w < 4) {
    unsigned short* dst = (w < 2) ? Qf : Kf;
    const int w2 = w & 1;                        // c64-half of Q or K
#pragma unroll
    for (int p = 0; p < 4; ++p) {
      const int o = w * 32 + p * 8 + lh * 4;     // global qkv channel
      float4_t bv = *(const float4_t*)(bs + o);
      ushort4_t pk4;
#pragma unroll
      for (int q = 0; q < 4; ++q) pk4[q] = f2bf(acc[p * 4 + q] + bv[q]);
      const int kkt = w2 * 2 + (p >> 1);
      *(ushort4_t*)(dst + ((((b * 128 + nt) * 4 + kkt) << 9)
                           + (l31 + 32 * (p & 1)) * 8 + lh * 4)) = pk4;
    }
  } else {
    const float bvs = bs[128 + (w - 4) * 32 + l31];
#pragma unroll
    for (int p = 0; p < 4; ++p) {
      ushort4_t pk4;
#pragma unroll
      for (int q = 0; q < 4; ++q) pk4[q] = f2bf(acc[p * 4 + q] + bvs);
      *(ushort4_t*)(Vf + (((((b * 128 + nt) * 2 + (w - 4)) * 2 + (p >> 1)) << 9)
                          + (l31 + 32 * (p & 1)) * 8 + lh * 4)) = pk4;
    }
  }
}

// ---------------------------------------------------------------------------
// k_attn: grid 256 x 512 thr (8 waves). Block: 64 q-rows; wave = m-parity
// (8-way, 16 iters of 32-m chunks), each wave covers both 32-n subtiles.
// ---------------------------------------------------------------------------
#define OS   68    // Oacc row stride (fp32)
#define OLS  72    // Ol row stride (bf16)
#define NACC (64 * OS + 64)

__device__ __forceinline__ void attn_step(
    const short8 kf[4], const short8 qf[4], const short8 vf[4],
    int lh, float16_t& oc0, float16_t& oc1, float& den)
{
  float16_t s = z16();
#pragma unroll
  for (int kk = 0; kk < 4; ++kk) s = MFMA(kf[kk], qf[kk], s);

  float p[16];
#pragma unroll
  for (int e = 0; e < 16; ++e) p[e] = PEXP(s[e]);
  {
    float d0 = (p[0] + p[1]) + (p[2] + p[3]);
    float d1 = (p[4] + p[5]) + (p[6] + p[7]);
    float d2 = (p[8] + p[9]) + (p[10] + p[11]);
    float d3 = (p[12] + p[13]) + (p[14] + p[15]);
    den += (d0 + d1) + (d2 + d3);
  }

  unsigned int u[8];
#pragma unroll
  for (int j = 0; j < 8; ++j) u[j] = pkbf(p[2 * j], p[2 * j + 1]);

  // cross-half exchange -> P frag [outer n = l31][k = m] (A/B layouts match)
  unsigned int t0 = lh ? u[0] : u[2];
  unsigned int t1 = lh ? u[1] : u[3];
  unsigned int t2 = lh ? u[4] : u[6];
  unsigned int t3 = lh ? u[5] : u[7];
  unsigned int r0 = __shfl_xor(t0, 32);
  unsigned int r1 = __shfl_xor(t1, 32);
  unsigned int r2 = __shfl_xor(t2, 32);
  unsigned int r3 = __shfl_xor(t3, 32);
  uint4_t w0, w1;
  w0[0] = lh ? r0 : u[0]; w0[1] = lh ? r1 : u[1];
  w0[2] = lh ? u[2] : r0; w0[3] = lh ? u[3] : r1;
  w1[0] = lh ? r2 : u[4]; w1[1] = lh ? r3 : u[5];
  w1[2] = lh ? u[6] : r2; w1[3] = lh ? u[7] : r3;
  short8 pf0 = __builtin_bit_cast(short8, w0);   // ks=0 (m 0..15)
  short8 pf1 = __builtin_bit_cast(short8, w1);   // ks=1 (m 16..31)

  // O[n rows][c cols]: A = P, B = Vf
  oc0 = MFMA(pf0, vf[0], oc0);   // ct=0, ks=0
  oc0 = MFMA(pf1, vf[1], oc0);   // ct=0, ks=1
  oc1 = MFMA(pf0, vf[2], oc1);   // ct=1, ks=0
  oc1 = MFMA(pf1, vf[3], oc1);   // ct=1, ks=1
}

__global__ __launch_bounds__(512, 2) void k_attn(
    const unsigned short* __restrict__ Qf, const unsigned short* __restrict__ Kf,
    const unsigned short* __restrict__ Vf, const unsigned short* __restrict__ wps,
    const float* __restrict__ pb, float* __restrict__ out)
{
  __shared__ float Oacc[NACC];                       // O[n][c] partial + den tail
  __shared__ __align__(16) unsigned short Ol[64 * OLS];

  const int id = blockIdx.x;
  const int b  = (id >> 1) & 3;
  const int nt = (id & 1) | ((id >> 3) << 1);        // 0..63
  const int t  = threadIdx.x;
  const int wv = t >> 6, lane = t & 63, l31 = lane & 31, lh = lane >> 5;

  for (int i = t; i < NACC; i += 512) Oacc[i] = 0.0f;

  // Q frags for both 32-n subtiles (coalesced 1KB loads)
  short8 qf[2][4];
#pragma unroll
  for (int n2 = 0; n2 < 2; ++n2)
#pragma unroll
    for (int kk = 0; kk < 4; ++kk)
      qf[n2][kk] = ld8(Qf + (((b * 128 + nt * 2 + n2) * 4 + kk) << 9) + lane * 8);

  const unsigned short* kfb = Kf + (((b * 128 + wv) * 4) << 9) + lane * 8;
  const unsigned short* vfb = Vf + (((b * 128 + wv) * 4) << 9) + lane * 8;

  __syncthreads();   // Oacc zeroed

  float16_t oc00 = z16(), oc01 = z16(), oc10 = z16(), oc11 = z16();
  float den0 = 0.0f, den1 = 0.0f;

  short8 kf[2][4], vf[2][4];
#pragma unroll
  for (int kk = 0; kk < 4; ++kk) {
    kf[0][kk] = ld8(kfb + (kk << 9));
    vf[0][kk] = ld8(vfb + (kk << 9));
  }

#pragma unroll 2
  for (int it = 0; it < 16; ++it) {
    const int cur = it & 1, nxt = cur ^ 1;
    if (it < 15) {
      const unsigned short* kp = kfb + (it + 1) * 16384;
      const unsigned short* vp = vfb + (it + 1) * 16384;
#pragma unroll
      for (int kk = 0; kk < 4; ++kk) {
        kf[nxt][kk] = ld8(kp + (kk << 9));
        vf[nxt][kk] = ld8(vp + (kk << 9));
      }
    }
    attn_step(kf[cur], qf[0], vf[cur], lh, oc00, oc01, den0);
    attn_step(kf[cur], qf[1], vf[cur], lh, oc10, oc11, den1);
  }

  den0 += __shfl_xor(den0, 32);
  den1 += __shfl_xor(den1, 32);

  // combine parities: O[n][c] (+ den) via LDS atomics
#pragma unroll
  for (int n2 = 0; n2 < 2; ++n2)
#pragma unroll
    for (int ct = 0; ct < 2; ++ct) {
      const float16_t& oa = n2 ? (ct ? oc11 : oc10) : (ct ? oc01 : oc00);
      const int cc = ct * 32 + l31;
#pragma unroll
      for (int e = 0; e < 16; ++e) {
        const int nr = n2 * 32 + (e & 3) + 8 * (e >> 2) + 4 * lh;
        atomicAdd(&Oacc[nr * OS + cc], oa[e]);
      }
    }
  if (lane < 32) {
    atomicAdd(&Oacc[64 * OS + l31], den0);
    atomicAdd(&Oacc[64 * OS + 32 + l31], den1);
  }
  __syncthreads();

  // normalize + cast -> Ol[n][c] bf16
  {
    const int nloc = t >> 3, c8 = (t & 7) * 8;
    float4_t s0 = *(float4_t*)&Oacc[nloc * OS + c8];
    float4_t s1 = *(float4_t*)&Oacc[nloc * OS + c8 + 4];
    const float r = 1.0f / Oacc[64 * OS + nloc];
    uint4_t o4;
    o4[0] = pkbf(s0[0] * r, s0[1] * r);
    o4[1] = pkbf(s0[2] * r, s0[3] * r);
    o4[2] = pkbf(s1[0] * r, s1[1] * r);
    o4[3] = pkbf(s1[2] * r, s1[3] * r);
    *(uint4_t*)&Ol[nloc * OLS + c8] = o4;
  }
  __syncthreads();

  // fused proj: wave wv -> o-tile wv (32 o), both n-subtiles
  float16_t f0 = z16(), f1 = z16();
#pragma unroll
  for (int kk = 0; kk < 4; ++kk) {
    short8 af = ld8(wps + (((wv * 4 + kk) << 6) + lane) * 8);
    short8 b0 = ld8(&Ol[l31 * OLS + kk * 16 + lh * 8]);
    short8 b1 = ld8(&Ol[(32 + l31) * OLS + kk * 16 + lh * 8]);
    f0 = MFMA(af, b0, f0);
    f1 = MFMA(af, b1, f1);
  }
  const int n0 = nt * 64;
#pragma unroll
  for (int e = 0; e < 16; ++e) {
    const int o = wv * 32 + (e & 3) + 8 * (e >> 2) + 4 * lh;
    const float bv = pb[o];
    out[((b * 256 + o) << 12) + n0 + l31]      = f0[e] + bv;
    out[((b * 256 + o) << 12) + n0 + 32 + l31] = f1[e] + bv;
  }
}

extern "C" void kernel_launch(void* const* d_in, const int* in_sizes, int n_in,
                              void* d_out, int out_size, void* d_ws, size_t ws_size,
                              hipStream_t stream) {
  const float* x      = (const float*)d_in[0];
  const float* qkv_w  = (const float*)d_in[1];
  const float* qkv_b  = (const float*)d_in[2];
  const float* proj_w = (const float*)d_in[3];
  const float* proj_b = (const float*)d_in[4];
  float* out = (float*)d_out;

  unsigned short* ws  = (unsigned short*)d_ws;
  unsigned short* qf  = ws + QOFF;
  unsigned short* kf  = ws + KOFF;
  unsigned short* vf  = ws + VOFF;
  unsigned short* wqs = ws + WQOFF;
  unsigned short* wps = ws + WPOFF;
  float*          bs  = (float*)(ws + BSOFF);

  k_prep<<<32, 256, 0, stream>>>(qkv_w, qkv_b, proj_w, wqs, wps, bs);
  k_qkv<<<512, 384, 0, stream>>>(x, wqs, bs, qf, kf, vf);
  k_attn<<<256, 512, 0, stream>>>(qf, kf, vf, wps, proj_b, out);
}

// Round 5
// 140.475 us; speedup vs baseline: 1.1793x; 1.0436x over previous
//
#include <hip/hip_runtime.h>

// EfficientAttention: x(4,256,64,64) -> qkv(192ch) -> attn(N=4096,c=64) -> proj(256ch)
// Frag-swizzled global layouts; V's k-slots permuted at production so the
// S^T result registers ARE the O-MFMA A-operand (no shfl transpose at all).
//   Qf/Kf: [b][chunk32][kk(4)][lane(64)][8]
//   Vf   : [b][chunk32][ct(2)ks(2)][lane(64)][j(8)] = producer reg order
// k_attn: 1024 thr (16 waves = 2 nsub x 8 m-parity), 16 iters/wave,
//         unnormalized online softmax, LDS-atomic combine, fused proj.

#define N_TOK 4096
#define CDIM  64
#define DIM   256
#define NBAT  4

typedef __attribute__((ext_vector_type(8)))  short          short8;
typedef __attribute__((ext_vector_type(8)))  unsigned short ushort8_t;
typedef __attribute__((ext_vector_type(4)))  unsigned short ushort4_t;
typedef __attribute__((ext_vector_type(4)))  unsigned int   uint4_t;
typedef __attribute__((ext_vector_type(4)))  float          float4_t;
typedef __attribute__((ext_vector_type(16))) float          float16_t;

#if __has_builtin(__builtin_amdgcn_exp2f)
#define QSC  0.18033688011112042f   /* 0.125 * log2(e): p = exp2(s) */
#define PEXP(x) __builtin_amdgcn_exp2f(x)
#else
#define QSC  0.125f
#define PEXP(x) __expf(x)
#endif

__device__ __forceinline__ unsigned short f2bf(float f) {
  unsigned int u = __builtin_bit_cast(unsigned int, f);
  u += 0x7fffu + ((u >> 16) & 1u);            // RNE
  return (unsigned short)(u >> 16);
}

__device__ __forceinline__ unsigned int pkbf(float a, float b) {
  return (unsigned int)f2bf(a) | ((unsigned int)f2bf(b) << 16);
}

__device__ __forceinline__ short8 ld8(const unsigned short* p) {
  return __builtin_bit_cast(short8, *(const ushort8_t*)p);
}

__device__ __forceinline__ float16_t z16() {
  float16_t r;
#pragma unroll
  for (int i = 0; i < 16; ++i) r[i] = 0.0f;
  return r;
}

#define MFMA(a, b, c) __builtin_amdgcn_mfma_f32_32x32x16_bf16((a), (b), (c), 0, 0, 0)

// ws layout (u16 units)
#define QOFF  0                // 4*128*4*512 = 1048576
#define KOFF  1048576
#define VOFF  2097152
#define WQOFF 3145728          // 192*256
#define WPOFF 3194880          // 256*64
#define BSOFF 3211264          // scaled qkv bias, fp32 (192)

// ---------------------------------------------------------------------------
// k_prep: grid 32 x 256. Swizzle qkv_w / proj_w into frag layouts (bf16),
// bias -> fp32 with Q-scale fold.
// ---------------------------------------------------------------------------
__global__ void k_prep(const float* __restrict__ qw, const float* __restrict__ qb,
                       const float* __restrict__ pw, unsigned short* __restrict__ wqs,
                       unsigned short* __restrict__ wps, float* __restrict__ bs)
{
  const int g = blockIdx.x * 256 + threadIdx.x;   // 0..8191
  if (g < 6144) {                                  // wqs: grp = w6*16+kk
    const int lane = g & 63, grp = g >> 6;
    const int w6 = grp >> 4, kk = grp & 15;
    const int o = w6 * 32 + (lane & 31);
    const int c = kk * 16 + (lane >> 5) * 8;
    const float sc = (o < 64) ? QSC : 1.0f;
    const float* src = qw + o * 256 + c;
    ushort8_t u;
#pragma unroll
    for (int j = 0; j < 8; ++j) u[j] = f2bf(src[j] * sc);
    *(ushort8_t*)(wqs + g * 8) = u;
  } else {                                         // wps: grp = wv*4+kk
    const int i = g - 6144;                        // < 2048
    const int lane = i & 63, grp = i >> 6;
    const int wv = grp >> 2, kk = grp & 3;
    const int o = wv * 32 + (lane & 31);
    const int c = kk * 16 + (lane >> 5) * 8;
    const float* src = pw + o * 64 + c;
    ushort8_t u;
#pragma unroll
    for (int j = 0; j < 8; ++j) u[j] = f2bf(src[j]);
    *(ushort8_t*)(wps + i * 8) = u;
  }
  if (g < 48) {
    float4_t f = *(const float4_t*)(qb + g * 4);
    float4_t o;
#pragma unroll
    for (int j = 0; j < 4; ++j) o[j] = f[j] * ((g * 4 + j) < 64 ? QSC : 1.0f);
    *(float4_t*)(bs + g * 4) = o;
  }
}

// ---------------------------------------------------------------------------
// k_qkv: grid 512 x 384 thr (6 waves). Block: n-tile of 32, all 192 o.
// Waves 0-3 (Q,K): C[o rows][n col=l31] -> frag stores.
// Waves 4-5 (V):   operands swapped -> C[token rows][c col], stored in the
//                  producer's own register order (= permuted k-slots).
// ---------------------------------------------------------------------------
#define RS 132   // Xl row stride in dwords

__global__ __launch_bounds__(384, 3) void k_qkv(
    const float* __restrict__ x, const unsigned short* __restrict__ wqs,
    const float* __restrict__ bs, unsigned short* __restrict__ Qf,
    unsigned short* __restrict__ Kf, unsigned short* __restrict__ Vf)
{
  __shared__ unsigned int Xl[32 * RS];
  const int id = blockIdx.x;
  const int b  = (id >> 1) & 3;
  const int nt = (id & 1) | ((id >> 3) << 1);   // 0..127 (32-token chunk)
  const int t  = threadIdx.x;
  const int n0g = nt * 32;

  if (t < 256) {
    const int n0  = (t & 7) * 4;
    const int cpb = t >> 3;                      // 0..31
#pragma unroll
    for (int p = 0; p < 4; ++p) {
      const int cp = cpb + 32 * p, c = cp * 2;
      const float* xb = x + (((size_t)(b * DIM + c)) << 12) + n0g + n0;
      float4_t a = *(const float4_t*)xb;
      float4_t d = *(const float4_t*)(xb + 4096);
#pragma unroll
      for (int j = 0; j < 4; ++j)
        Xl[(n0 + j) * RS + cp] = pkbf(a[j], d[j]);
    }
  }
  __syncthreads();

  const int w = t >> 6, lane = t & 63, l31 = lane & 31, lh = lane >> 5;
  float16_t acc = z16();
  const unsigned short* wrow = wqs + ((w * 16) << 9) + lane * 8;
  const unsigned int*   xrow = &Xl[l31 * RS + lh * 4];

  if (w < 4) {
#pragma unroll
    for (int kk = 0; kk < 16; ++kk) {
      short8 bfr = __builtin_bit_cast(short8, *(const uint4_t*)(xrow + kk * 8));
      short8 afr = ld8(wrow + (kk << 9));
      acc = MFMA(afr, bfr, acc);                 // C[o rows][n cols]
    }
  } else {
#pragma unroll
    for (int kk = 0; kk < 16; ++kk) {
      short8 bfr = __builtin_bit_cast(short8, *(const uint4_t*)(xrow + kk * 8));
      short8 afr = ld8(wrow + (kk << 9));
      acc = MFMA(bfr, afr, acc);                 // C[token rows][c cols]
    }
  }

  if (w < 4) {
    unsigned short* dst = (w < 2) ? Qf : Kf;
    const int w2 = w & 1;                        // c64-half of Q or K
#pragma unroll
    for (int p = 0; p < 4; ++p) {
      const int o = w * 32 + p * 8 + lh * 4;     // global qkv channel
      float4_t bv = *(const float4_t*)(bs + o);
      ushort4_t pk4;
#pragma unroll
      for (int q = 0; q < 4; ++q) pk4[q] = f2bf(acc[p * 4 + q] + bv[q]);
      const int kkt = w2 * 2 + (p >> 1);
      *(ushort4_t*)(dst + ((((b * 128 + nt) * 4 + kkt) << 9)
                           + (l31 + 32 * (p & 1)) * 8 + lh * 4)) = pk4;
    }
  } else {
    const int ct = w - 4;                        // c-group of V
    const float bvs = bs[128 + ct * 32 + l31];
#pragma unroll
    for (int ks = 0; ks < 2; ++ks) {
      ushort8_t pk8;
#pragma unroll
      for (int j = 0; j < 8; ++j) pk8[j] = f2bf(acc[ks * 8 + j] + bvs);
      *(ushort8_t*)(Vf + ((((b * 128 + nt) * 4 + ct * 2 + ks) << 9)
                          + lane * 8)) = pk8;
    }
  }
}

// ---------------------------------------------------------------------------
// k_attn: grid 256 x 1024 thr (16 waves, 4/SIMD). Block: 64 q-rows.
// wave wv: nsub = wv&1 (32-n subtile), par = wv>>1 (8-way m-parity),
// 16 iters of 32-m chunks. No LDS / no shfl in the loop.
// ---------------------------------------------------------------------------
#define OS   68    // Oacc row stride (fp32)
#define OLS  72    // Ol row stride (bf16)
#define NACC (64 * OS + 64)

__global__ __launch_bounds__(1024, 4) void k_attn(
    const unsigned short* __restrict__ Qf, const unsigned short* __restrict__ Kf,
    const unsigned short* __restrict__ Vf, const unsigned short* __restrict__ wps,
    const float* __restrict__ pb, float* __restrict__ out)
{
  __shared__ float Oacc[NACC];                       // O[n][c] partial + den tail
  __shared__ __align__(16) unsigned short Ol[64 * OLS];

  const int id = blockIdx.x;
  const int b  = (id >> 1) & 3;
  const int nt = (id & 1) | ((id >> 3) << 1);        // 0..63
  const int t  = threadIdx.x;
  const int wv = t >> 6, lane = t & 63, l31 = lane & 31, lh = lane >> 5;
  const int nsub = wv & 1, par = wv >> 1;

  for (int i = t; i < NACC; i += 1024) Oacc[i] = 0.0f;

  // Q frags (pre-scaled by QSC via k_prep weight fold)
  short8 qf[4];
#pragma unroll
  for (int kk = 0; kk < 4; ++kk)
    qf[kk] = ld8(Qf + (((b * 128 + nt * 2 + nsub) * 4 + kk) << 9) + lane * 8);

  const unsigned short* kfb = Kf + (((b * 128 + par) * 4) << 9) + lane * 8;
  const unsigned short* vfb = Vf + (((b * 128 + par) * 4) << 9) + lane * 8;

  __syncthreads();   // Oacc zeroed

  float16_t oc0 = z16(), oc1 = z16();
  float den = 0.0f;

  short8 kf[4], vf[4];
#pragma unroll
  for (int kk = 0; kk < 4; ++kk) {
    kf[kk] = ld8(kfb + (kk << 9));
    vf[kk] = ld8(vfb + (kk << 9));
  }

  for (int it = 0; it < 16; ++it) {
    // S^T tile: lane col n = l31, row m = (e&3)+8*(e>>2)+4*lh
    float16_t s = z16();
#pragma unroll
    for (int kk = 0; kk < 4; ++kk) s = MFMA(kf[kk], qf[kk], s);

    // prefetch next K chunk (consumed next iter; overlaps exp/pack/O-MFMA)
    if (it < 15) {
      const unsigned short* kp = kfb + (it + 1) * 16384;
#pragma unroll
      for (int kk = 0; kk < 4; ++kk) kf[kk] = ld8(kp + (kk << 9));
    }

    float p[16];
#pragma unroll
    for (int e = 0; e < 16; ++e) p[e] = PEXP(s[e]);
    {
      float d0 = (p[0] + p[1]) + (p[2] + p[3]);
      float d1 = (p[4] + p[5]) + (p[6] + p[7]);
      float d2 = (p[8] + p[9]) + (p[10] + p[11]);
      float d3 = (p[12] + p[13]) + (p[14] + p[15]);
      den += (d0 + d1) + (d2 + d3);
    }

    // S^T regs ARE the A-operand of the O-MFMA (V k-slots pre-permuted):
    // slot (h=lh, j) of pf_ks holds token m = 16ks + 4h + (j&3) + 8*(j>>2).
    uint4_t w0, w1;
#pragma unroll
    for (int j = 0; j < 4; ++j) {
      w0[j] = pkbf(p[2 * j], p[2 * j + 1]);
      w1[j] = pkbf(p[8 + 2 * j], p[9 + 2 * j]);
    }
    short8 pf0 = __builtin_bit_cast(short8, w0);
    short8 pf1 = __builtin_bit_cast(short8, w1);

    oc0 = MFMA(pf0, vf[0], oc0);   // ct=0, ks=0
    oc0 = MFMA(pf1, vf[1], oc0);   // ct=0, ks=1
    oc1 = MFMA(pf0, vf[2], oc1);   // ct=1, ks=0
    oc1 = MFMA(pf1, vf[3], oc1);   // ct=1, ks=1

    if (it < 15) {
      const unsigned short* vp = vfb + (it + 1) * 16384;
#pragma unroll
      for (int kk = 0; kk < 4; ++kk) vf[kk] = ld8(vp + (kk << 9));
    }
  }

  den += __shfl_xor(den, 32);   // combine lane halves (m coverage)

  // combine parities: O[n][c] (+ den) via LDS atomics
#pragma unroll
  for (int ct = 0; ct < 2; ++ct) {
    const float16_t& oa = ct ? oc1 : oc0;
    const int cc = ct * 32 + l31;
#pragma unroll
    for (int e = 0; e < 16; ++e) {
      const int nr = nsub * 32 + (e & 3) + 8 * (e >> 2) + 4 * lh;
      atomicAdd(&Oacc[nr * OS + cc], oa[e]);
    }
  }
  if (lane < 32) atomicAdd(&Oacc[64 * OS + nsub * 32 + l31], den);
  __syncthreads();

  // normalize + cast -> Ol[n][c] bf16  (1024 threads: 16 thr/row x 4 ch)
  {
    const int nloc = t >> 4, c4 = (t & 15) * 4;
    float4_t s0 = *(float4_t*)&Oacc[nloc * OS + c4];
    const float r = 1.0f / Oacc[64 * OS + nloc];
    ushort4_t o4;
#pragma unroll
    for (int j = 0; j < 4; ++j) o4[j] = f2bf(s0[j] * r);
    *(ushort4_t*)&Ol[nloc * OLS + c4] = o4;
  }
  __syncthreads();

  // fused proj: wave wv -> o-tile (wv>>1), n-subtile (wv&1)
  float16_t f0 = z16();
  const int ot = wv >> 1;
#pragma unroll
  for (int kk = 0; kk < 4; ++kk) {
    short8 af = ld8(wps + (((ot * 4 + kk) << 6) + lane) * 8);
    short8 b0 = ld8(&Ol[(nsub * 32 + l31) * OLS + kk * 16 + lh * 8]);
    f0 = MFMA(af, b0, f0);
  }
  const int n0 = nt * 64 + nsub * 32;
#pragma unroll
  for (int e = 0; e < 16; ++e) {
    const int o = ot * 32 + (e & 3) + 8 * (e >> 2) + 4 * lh;
    out[((b * 256 + o) << 12) + n0 + l31] = f0[e] + pb[o];
  }
}

extern "C" void kernel_launch(void* const* d_in, const int* in_sizes, int n_in,
                              void* d_out, int out_size, void* d_ws, size_t ws_size,
                              hipStream_t stream) {
  const float* x      = (const float*)d_in[0];
  const float* qkv_w  = (const float*)d_in[1];
  const float* qkv_b  = (const float*)d_in[2];
  const float* proj_w = (const float*)d_in[3];
  const float* proj_b = (const float*)d_in[4];
  float* out = (float*)d_out;

  unsigned short* ws  = (unsigned short*)d_ws;
  unsigned short* qf  = ws + QOFF;
  unsigned short* kf  = ws + KOFF;
  unsigned short* vf  = ws + VOFF;
  unsigned short* wqs = ws + WQOFF;
  unsigned short* wps = ws + WPOFF;
  float*          bs  = (float*)(ws + BSOFF);

  k_prep<<<32, 256, 0, stream>>>(qkv_w, qkv_b, proj_w, wqs, wps, bs);
  k_qkv<<<512, 384, 0, stream>>>(x, wqs, bs, qf, kf, vf);
  k_attn<<<256, 1024, 0, stream>>>(qf, kf, vf, wps, proj_b, out);
}